// Round 13
// baseline (187.423 us; speedup 1.0000x reference)
//
#include <hip/hip_runtime.h>
#include <hip/hip_bf16.h>

#define N_ATOMS 50000
#define N_EDGES 800000
#define DEG 16
#define N_MOL 1000
#define NA 23
#define NB 7
#define O0 32
#define O1 12
#define O2 8
#define OZ 21          // folded output width: w0f(7) | w1f(7) | w2f(7)
#define NT 2           // N-tiles of 16
#define ZROW 64        // bf16 per z-row: [b*8+c] c=0..7; c8 at 56+b; [63]=0  (128 B = 1 line)
#define NPW 4          // nodes per wave in k2
#define VFRAG_N 896    // 14 fragments * 64 lanes, short8 each (14336 B)

typedef __attribute__((ext_vector_type(8))) short short8;
typedef __attribute__((ext_vector_type(4))) float floatx4;

__device__ __forceinline__ unsigned short bfbits(float f) {  // f32 -> bf16 RNE
    unsigned u = __float_as_uint(f);
    u += 0x7FFFu + ((u >> 16) & 1u);
    return (unsigned short)(u >> 16);
}
__device__ __forceinline__ float bf_lo(unsigned u) { return __uint_as_float(u << 16); }
__device__ __forceinline__ float bf_hi(unsigned u) { return __uint_as_float(u & 0xFFFF0000u); }
__device__ __forceinline__ float wred4(float v) {  // sum over the 4 quads
    v += __shfl_xor(v, 16, 64); v += __shfl_xor(v, 32, 64); return v;
}
// 16B-per-lane hardware gather into LDS: per-lane global src, wave-uniform LDS
// base; HW writes lane i at base + i*16 (m104/m173). No VGPR held in flight.
__device__ __forceinline__ void gather16_lds(const void* gaddr, void* laddr) {
    __builtin_amdgcn_global_load_lds(
        (const __attribute__((address_space(1))) unsigned*)gaddr,
        (__attribute__((address_space(3))) unsigned*)laddr, 16, 0, 0);
}

// ---------------- K_prep: zero out + Vfrag (W1*W2) + x_bf + pos4 + evec ------
__global__ void k_prep(const float* __restrict__ W1_0, const float* __restrict__ W1_1,
                       const float* __restrict__ W1_2,
                       const float* __restrict__ W2_0, const float* __restrict__ W2_1,
                       const float* __restrict__ W2_2,
                       const float* __restrict__ x, const float* __restrict__ pos,
                       const int* __restrict__ edge_src,
                       unsigned short* __restrict__ Vfrag,
                       unsigned short* __restrict__ x_bf, float4* __restrict__ pos4,
                       float4* __restrict__ evec,
                       float* __restrict__ out) {
    int idx = blockIdx.x * 256 + threadIdx.x;
    if (idx < N_MOL) out[idx] = 0.0f;
    if (idx < VFRAG_N * 8) {
        int j    = idx & 7;
        int lane = (idx >> 3) & 63;
        int st   = idx >> 9;           // 0..13 = s*NT+t
        int s = st >> 1, t = st & 1;
        int a = (lane >> 4) * 8 + j, o = t * 16 + (lane & 15);
        float val = 0.f;
        if (a < NA && o < OZ) {
            const float n1 = 0.07881104062391006f;   // 1/sqrt(23*7)
            const float q  = 0.25f;                  // inv_sqrt_deg (deg==16)
            float acc = 0.f;
            if (o < 7) {
                const float c0 = 0.06681531047810609f;   // 1/sqrt(32*7)
                const float* w1 = W1_0 + (a * NB + s) * O0;
                for (int k = 0; k < O0; k++) acc += w1[k] * W2_0[k * NB + o];
                val = acc * (n1 * c0 * q);
            } else if (o < 14) {
                const float c1 = 0.06299407883487121f;   // 1/(sqrt(12*7)*sqrt(3))
                const float* w1 = W1_1 + (a * NB + s) * O1;
                for (int k = 0; k < O1; k++) acc += w1[k] * W2_1[k * NB + (o - 7)];
                val = acc * (n1 * c1 * q);
            } else {
                const float c2 = 0.05976143046671968f;   // 1/(sqrt(8*7)*sqrt(5))
                const float* w1 = W1_2 + (a * NB + s) * O2;
                for (int k = 0; k < O2; k++) acc += w1[k] * W2_2[k * NB + (o - 14)];
                val = acc * (n1 * c2 * q);
            }
        }
        Vfrag[idx] = bfbits(val);
    }
    if (idx < N_ATOMS) {
        float4 p; p.x = pos[idx * 3 + 0]; p.y = pos[idx * 3 + 1];
        p.z = pos[idx * 3 + 2]; p.w = 0.f;
        pos4[idx] = p;
    }
    if (idx < N_ATOMS * 32) {
        int n = idx >> 5, a = idx & 31;
        x_bf[idx] = bfbits((a < NA) ? x[n * NA + a] : 0.f);
    }
    if (idx < N_EDGES) {
        // per-edge vec = pos[src] - pos[dst]
        int s = edge_src[idx];
        int d = idx >> 4;
        float4 v;
        v.x = pos[s * 3 + 0] - pos[d * 3 + 0];
        v.y = pos[s * 3 + 1] - pos[d * 3 + 1];
        v.z = pos[s * 3 + 2] - pos[d * 3 + 2];
        v.w = 0.f;
        evec[idx] = v;
    }
}

// ---------------- K2: per-node MFMA GEMM (N=21 folded); bf16 z-row epilogue --
__global__ __launch_bounds__(256, 5) void k2_s(const float4* __restrict__ pos4,
        const unsigned short* __restrict__ x_bf, const float* __restrict__ edge_attr,
        const int* __restrict__ edge_src, const unsigned short* __restrict__ Vfrag,
        unsigned short* __restrict__ zbuf) {
    __shared__ short8 wfrag[VFRAG_N];          // 14336 B, shared by 4 waves
    __shared__ float hbuf[4][16][8];
    const int tid  = threadIdx.x;
    const int wid  = tid >> 6;
    const int lane = tid & 63;
    const int lcol = lane & 15;
    const int quad = lane >> 4;

    {   // cooperative stage of the prebuilt folded-weight fragments
        uint4* dst = (uint4*)wfrag;
        const uint4* src4 = (const uint4*)Vfrag;
        for (int i = tid; i < VFRAG_N; i += 256) dst[i] = src4[i];
    }
    __syncthreads();

    const int wgid = __builtin_amdgcn_readfirstlane(blockIdx.x * 4 + wid);
    const int base = wgid * NPW;
    if (base >= N_ATOMS) return;

    float (*hb)[8] = hbuf[wid];
    const float s3 = 1.7320508075688772f, s15 = 3.872983346207417f;
    const float s5h = 1.118033988749895f, s15h = 1.9364916731037085f;

    auto clampn = [&](int i) { int nn = base + i; return nn < N_ATOMS ? nn : N_ATOMS - 1; };
    int s0v = edge_src[clampn(0) * DEG + lcol];
    int s1v = edge_src[clampn(1) * DEG + lcol];
    uint4 xu0 = *(const uint4*)(x_bf + s0v * 32 + quad * 8);
    float4 pp0 = pos4[s0v];
    float e0v[NB];
    {
        const float* p = edge_attr + ((size_t)clampn(0) * DEG + lcol) * NB;
        #pragma unroll
        for (int b = 0; b < NB; b++) e0v[b] = p[b];
    }

    #pragma unroll 1
    for (int i = 0; i < NPW; i++) {
        const int n = base + i;
        if (n >= N_ATOMS) break;
        // ---- prefetch next stage ----
        int s2v = edge_src[clampn(i + 2 < NPW ? i + 2 : i) * DEG + lcol];
        uint4 xu1 = *(const uint4*)(x_bf + s1v * 32 + quad * 8);
        float4 pp1 = pos4[s1v];
        float e1v[NB];
        {
            const float* p = edge_attr + ((size_t)clampn(i + 1 < NPW ? i + 1 : i) * DEG + lcol) * NB;
            #pragma unroll
            for (int b = 0; b < NB; b++) e1v[b] = p[b];
        }
        // ---- unpack this node's x slice ----
        float xf[8];
        xf[0] = bf_lo(xu0.x); xf[1] = bf_hi(xu0.x);
        xf[2] = bf_lo(xu0.y); xf[3] = bf_hi(xu0.y);
        xf[4] = bf_lo(xu0.z); xf[5] = bf_hi(xu0.z);
        xf[6] = bf_lo(xu0.w); xf[7] = bf_hi(xu0.w);

        // ---- h-factors for node n (lanes 0..15): [sh1(3), sh2(5)] ----
        const float4 pd = pos4[n];
        if (lane < 16) {
            const float vx = pp0.x - pd.x, vy = pp0.y - pd.y, vz = pp0.z - pd.z;
            hb[lane][0] = s3 * vx;  hb[lane][1] = s3 * vy;  hb[lane][2] = s3 * vz;
            hb[lane][3] = s15 * vx * vy;
            hb[lane][4] = s15 * vy * vz;
            hb[lane][5] = s5h * (2.f * vz * vz - vx * vx - vy * vy);
            hb[lane][6] = s15 * vx * vz;
            hb[lane][7] = s15h * (vx * vx - vy * vy);
        }
        // ---- MFMA: 7 K-steps x 2 N-tiles (folded weights) ----
        floatx4 acc0 = {0.f,0.f,0.f,0.f}, acc1 = {0.f,0.f,0.f,0.f};
        #pragma unroll
        for (int s = 0; s < 7; s++) {
            const float eb = e0v[s];
            union { short8 v; unsigned u[4]; } af;
            #pragma unroll
            for (int j = 0; j < 8; j += 2) {
                float2 pr; pr.x = xf[j] * eb; pr.y = xf[j + 1] * eb;
                __hip_bfloat162 bb = __float22bfloat162_rn(pr);
                af.u[j >> 1] = *(unsigned*)&bb;
            }
            acc0 = __builtin_amdgcn_mfma_f32_16x16x32_bf16(af.v, wfrag[(s*NT+0)*64 + lane], acc0, 0, 0, 0);
            acc1 = __builtin_amdgcn_mfma_f32_16x16x32_bf16(af.v, wfrag[(s*NT+1)*64 + lane], acc1, 0, 0, 0);
        }
        // ---- epilogue: produce bf16 z-row (63 vals + pad) directly ----
        float4 hA[4], hB[4];
        #pragma unroll
        for (int r = 0; r < 4; r++) {
            int e = quad * 4 + r;
            hA[r] = *(const float4*)&hb[e][0];   // sh1 x,y,z | sh2 m0
            hB[r] = *(const float4*)&hb[e][4];   // sh2 m1..m4
        }
        unsigned short* sr = zbuf + (size_t)n * ZROW;
        const bool useA = (lcol >= 14);          // z2 source: acc0 cols 14,15 else acc1 cols 0..4
        float v0 = acc0[0] + acc0[1] + acc0[2] + acc0[3];
        float u0 = 0.f, u1 = 0.f, u2 = 0.f;
        float t0 = 0.f, t1 = 0.f, t2 = 0.f, t3 = 0.f, t4 = 0.f;
        #pragma unroll
        for (int r = 0; r < 4; r++) {
            float m0 = acc0[r], m1 = acc1[r];
            u0 += m0 * hA[r].x; u1 += m0 * hA[r].y; u2 += m0 * hA[r].z;
            float mz = useA ? m0 : m1;
            t0 += mz * hA[r].w; t1 += mz * hB[r].x; t2 += mz * hB[r].y;
            t3 += mz * hB[r].z; t4 += mz * hB[r].w;
        }
        v0 = wred4(v0);
        u0 = wred4(u0); u1 = wred4(u1); u2 = wred4(u2);
        t0 = wred4(t0); t1 = wred4(t1); t2 = wred4(t2); t3 = wred4(t3); t4 = wred4(t4);
        if (quad == 0) {
            if (lcol < 7) sr[lcol * 8] = bfbits(v0);                // c=0
            else if (lcol < 14) {                                   // c=1..3 (sh1)
                int b = lcol - 7;
                sr[b * 8 + 1] = bfbits(u0); sr[b * 8 + 2] = bfbits(u1); sr[b * 8 + 3] = bfbits(u2);
            }
            if (lcol >= 14 || lcol < 5) {                           // c=4..8 (sh2)
                int b = useA ? (lcol - 14) : (lcol + 2);
                sr[b * 8 + 4] = bfbits(t0); sr[b * 8 + 5] = bfbits(t1); sr[b * 8 + 6] = bfbits(t2);
                sr[b * 8 + 7] = bfbits(t3); sr[56 + b] = bfbits(t4);
            }
            if (lcol == 5) sr[63] = 0;   // pad (must be finite)
        }
        // ---- rotate pipeline ----
        s0v = s1v; s1v = s2v;
        xu0 = xu1; pp0 = pp1;
        #pragma unroll
        for (int b = 0; b < NB; b++) e0v[b] = e1v[b];
    }
}

// ---------------- K3 v7: z gather via global_load_lds (VGPR-free MLP) --------
// Wave = 64 edges = 4 dst nodes; 8-lane group g = edge, role r = b index.
// All 8 z-row gathers are issued as global_load_lds (no VGPR held in flight ->
// 64 lines outstanding per wave), ONE vmcnt(0), then ds_read_b128 consume.
__global__ __launch_bounds__(256, 4) void k3_g(const float4* __restrict__ evec,
        const float* __restrict__ edge_attr, const int* __restrict__ edge_src,
        const unsigned short* __restrict__ zbuf, float* __restrict__ out) {
    __shared__ __align__(16) unsigned char zstage[4][8192];   // 8 KB per wave
    const int tid  = threadIdx.x;
    const int wid  = tid >> 6;
    const int lane = tid & 63;
    const int g    = lane >> 3;                 // edge-group (0..7)
    const int r    = lane & 7;                  // role = b index
    const int wgid = __builtin_amdgcn_readfirstlane(blockIdx.x * 4 + wid);
    const int ebase = wgid * 64;                // 64 edges = 4 dst nodes
    const int nbase = ebase >> 4;
    char* zs = (char*)&zstage[wid][0];

    // ---- src ids (coalesced) ----
    int sj[8];
    #pragma unroll
    for (int j = 0; j < 8; j++) sj[j] = edge_src[ebase + j * 8 + g];

    // ---- issue ALL 8 z-row gathers to LDS (64 lines in flight, 0 VGPRs) ----
    #pragma unroll
    for (int j = 0; j < 8; j++)
        gather16_lds(zbuf + (size_t)sj[j] * ZROW + r * 8, zs + j * 1024);

    // ---- coalesced streams (overlap with the gathers) ----
    float4 ev[8];                               // 128 B/instr
    #pragma unroll
    for (int j = 0; j < 8; j++) ev[j] = evec[ebase + j * 8 + g];
    float eav[8];                               // 224 B/instr
    #pragma unroll
    for (int j = 0; j < 8; j++)
        eav[j] = (r < NB) ? edge_attr[(size_t)(ebase + j * 8 + g) * NB + r] : 0.f;

    // ---- single drain, then consume from LDS ----
    asm volatile("s_waitcnt vmcnt(0)" ::: "memory");
    __builtin_amdgcn_sched_barrier(0);

    const float s3 = 1.7320508075688772f, s15 = 3.872983346207417f;
    const float s5h = 1.118033988749895f, s15h = 1.9364916731037085f;
    float accA = 0.f, accB = 0.f, accC = 0.f, accD = 0.f;   // nodes 0..3
    const int src7 = lane | 7;

    #pragma unroll
    for (int j = 0; j < 8; j++) {
        const float4 v = ev[j];
        const float h1 = s3 * v.x, h2 = s3 * v.y, h3 = s3 * v.z;
        const float h4 = s15 * v.x * v.y, h5 = s15 * v.y * v.z;
        const float h6 = s5h * (2.f * v.z * v.z - v.x * v.x - v.y * v.y);
        const float h7 = s15 * v.x * v.z, h8 = s15h * (v.x * v.x - v.y * v.y);

        const uint4 z = *(const uint4*)(zs + j * 1024 + lane * 16);  // ds_read_b128
        // c8[b=r]: halfword r of lane|7's chunk (slots 56..63) — R5-verified
        const unsigned w0 = (unsigned)__shfl((int)z.x, src7, 64);
        const unsigned w1 = (unsigned)__shfl((int)z.y, src7, 64);
        const unsigned w2 = (unsigned)__shfl((int)z.z, src7, 64);
        const unsigned w3 = (unsigned)__shfl((int)z.w, src7, 64);
        const unsigned wa = (r & 4) ? w2 : w0;
        const unsigned wb = (r & 4) ? w3 : w1;
        const unsigned wc = (r & 2) ? wb : wa;
        const float c8 = (r & 1) ? bf_hi(wc) : bf_lo(wc);

        float t = bf_lo(z.x)
                + h1 * bf_hi(z.x) + h2 * bf_lo(z.y) + h3 * bf_hi(z.y)
                + h4 * bf_lo(z.z) + h5 * bf_hi(z.z) + h6 * bf_lo(z.w)
                + h7 * bf_hi(z.w) + h8 * c8;
        float p = eav[j] * t;                   // r==7 lane contributes 0
        if (j < 2)      accA += p;
        else if (j < 4) accB += p;
        else if (j < 6) accC += p;
        else            accD += p;
    }

    // 4 full-wave reductions (one per node), one atomic each
    #pragma unroll
    for (int p = 0; p < 4; p++) {
        float a = (p == 0) ? accA : (p == 1) ? accB : (p == 2) ? accC : accD;
        #pragma unroll
        for (int off = 32; off >= 1; off >>= 1) a += __shfl_xor(a, off, 64);
        if (lane == p)
            atomicAdd(out + (nbase + p) / 50, a * 0.035355339059327376f);  // 0.25/sqrt(50)
    }
}

extern "C" void kernel_launch(void* const* d_in, const int* in_sizes, int n_in,
                              void* d_out, int out_size, void* d_ws, size_t ws_size,
                              hipStream_t stream) {
    const float* pos  = (const float*)d_in[0];
    const float* x    = (const float*)d_in[1];
    const float* ea   = (const float*)d_in[2];
    const float* W1_0 = (const float*)d_in[3];
    const float* W1_1 = (const float*)d_in[4];
    const float* W1_2 = (const float*)d_in[5];
    const float* W2_0 = (const float*)d_in[6];
    const float* W2_1 = (const float*)d_in[7];
    const float* W2_2 = (const float*)d_in[8];
    const int*   esrc = (const int*)d_in[9];
    float* out = (float*)d_out;

    char* ws = (char*)d_ws;
    unsigned short* Vfrag = (unsigned short*)ws;                         // 14336 B
    unsigned short* zbuf  = (unsigned short*)(ws + 32768);               // 6.4 MB (bf16 rows)
    unsigned short* x_bf  = (unsigned short*)(ws + 32768 + 6400000);     // 3.2 MB
    float4*         pos4  = (float4*)(ws + 32768 + 6400000 + 3200000);   // 800 KB
    float4*         evec  = (float4*)(ws + 32768 + 6400000 + 3200000 + 800000); // 12.8 MB

    hipLaunchKernelGGL(k_prep, dim3((N_ATOMS * 32 + 255) / 256), dim3(256), 0, stream,
                       W1_0, W1_1, W1_2, W2_0, W2_1, W2_2, x, pos, esrc,
                       Vfrag, x_bf, pos4, evec, out);
    hipLaunchKernelGGL(k2_s, dim3((N_ATOMS / NPW + 3) / 4), dim3(256), 0, stream,
                       pos4, x_bf, ea, esrc, Vfrag, zbuf);
    hipLaunchKernelGGL(k3_g, dim3(N_EDGES / 64 / 4), dim3(256), 0, stream,
                       evec, ea, esrc, zbuf, out);
}

// Round 14
// 179.783 us; speedup vs baseline: 1.0425x; 1.0425x over previous
//
#include <hip/hip_runtime.h>
#include <hip/hip_bf16.h>

#define N_ATOMS 50000
#define N_EDGES 800000
#define DEG 16
#define N_MOL 1000
#define NA 23
#define NB 7
#define O0 32
#define O1 12
#define O2 8
#define OZ 21          // folded output width: w0f(7) | w1f(7) | w2f(7)
#define NT 2           // N-tiles of 16
#define ZROW 64        // bf16 per z-row: [b*8+c] c=0..7; c8 at 56+b; [63]=0  (128 B = 1 line)
#define NPW 4          // nodes per wave in k2
#define VFRAG_N 896    // 14 fragments * 64 lanes, short8 each (14336 B)

typedef __attribute__((ext_vector_type(8))) short short8;
typedef __attribute__((ext_vector_type(4))) float floatx4;

__device__ __forceinline__ unsigned short bfbits(float f) {  // f32 -> bf16 RNE
    unsigned u = __float_as_uint(f);
    u += 0x7FFFu + ((u >> 16) & 1u);
    return (unsigned short)(u >> 16);
}
__device__ __forceinline__ float bf_lo(unsigned u) { return __uint_as_float(u << 16); }
__device__ __forceinline__ float bf_hi(unsigned u) { return __uint_as_float(u & 0xFFFF0000u); }
__device__ __forceinline__ float wred4(float v) {  // sum over the 4 quads
    v += __shfl_xor(v, 16, 64); v += __shfl_xor(v, 32, 64); return v;
}

// ---------------- K_prep: zero out + Vfrag (W1*W2) + x_bf + evec -------------
__global__ void k_prep(const float* __restrict__ W1_0, const float* __restrict__ W1_1,
                       const float* __restrict__ W1_2,
                       const float* __restrict__ W2_0, const float* __restrict__ W2_1,
                       const float* __restrict__ W2_2,
                       const float* __restrict__ x, const float* __restrict__ pos,
                       const int* __restrict__ edge_src,
                       unsigned short* __restrict__ Vfrag,
                       unsigned short* __restrict__ x_bf,
                       float4* __restrict__ evec,
                       float* __restrict__ out) {
    int idx = blockIdx.x * 256 + threadIdx.x;
    if (idx < N_MOL) out[idx] = 0.0f;
    if (idx < VFRAG_N * 8) {
        int j    = idx & 7;
        int lane = (idx >> 3) & 63;
        int st   = idx >> 9;           // 0..13 = s*NT+t
        int s = st >> 1, t = st & 1;
        int a = (lane >> 4) * 8 + j, o = t * 16 + (lane & 15);
        float val = 0.f;
        if (a < NA && o < OZ) {
            const float n1 = 0.07881104062391006f;   // 1/sqrt(23*7)
            const float q  = 0.25f;                  // inv_sqrt_deg (deg==16)
            float acc = 0.f;
            if (o < 7) {
                const float c0 = 0.06681531047810609f;   // 1/sqrt(32*7)
                const float* w1 = W1_0 + (a * NB + s) * O0;
                for (int k = 0; k < O0; k++) acc += w1[k] * W2_0[k * NB + o];
                val = acc * (n1 * c0 * q);
            } else if (o < 14) {
                const float c1 = 0.06299407883487121f;   // 1/(sqrt(12*7)*sqrt(3))
                const float* w1 = W1_1 + (a * NB + s) * O1;
                for (int k = 0; k < O1; k++) acc += w1[k] * W2_1[k * NB + (o - 7)];
                val = acc * (n1 * c1 * q);
            } else {
                const float c2 = 0.05976143046671968f;   // 1/(sqrt(8*7)*sqrt(5))
                const float* w1 = W1_2 + (a * NB + s) * O2;
                for (int k = 0; k < O2; k++) acc += w1[k] * W2_2[k * NB + (o - 14)];
                val = acc * (n1 * c2 * q);
            }
        }
        Vfrag[idx] = bfbits(val);
    }
    if (idx < N_ATOMS * 32) {
        int n = idx >> 5, a = idx & 31;
        x_bf[idx] = bfbits((a < NA) ? x[n * NA + a] : 0.f);
    }
    if (idx < N_EDGES) {
        // per-edge vec = pos[src] - pos[dst]
        int s = edge_src[idx];
        int d = idx >> 4;
        float4 v;
        v.x = pos[s * 3 + 0] - pos[d * 3 + 0];
        v.y = pos[s * 3 + 1] - pos[d * 3 + 1];
        v.z = pos[s * 3 + 2] - pos[d * 3 + 2];
        v.w = 0.f;
        evec[idx] = v;
    }
}

// ---------------- K2: per-node MFMA GEMM (N=21 folded); bf16 z-row epilogue --
// Geometry from evec (coalesced, 16 float4 per node) — no random pos4 gather.
__global__ __launch_bounds__(256, 5) void k2_s(const float4* __restrict__ evec,
        const unsigned short* __restrict__ x_bf, const float* __restrict__ edge_attr,
        const int* __restrict__ edge_src, const unsigned short* __restrict__ Vfrag,
        unsigned short* __restrict__ zbuf) {
    __shared__ short8 wfrag[VFRAG_N];          // 14336 B, shared by 4 waves
    __shared__ float hbuf[4][16][8];
    const int tid  = threadIdx.x;
    const int wid  = tid >> 6;
    const int lane = tid & 63;
    const int lcol = lane & 15;
    const int quad = lane >> 4;

    {   // cooperative stage of the prebuilt folded-weight fragments
        uint4* dst = (uint4*)wfrag;
        const uint4* src4 = (const uint4*)Vfrag;
        for (int i = tid; i < VFRAG_N; i += 256) dst[i] = src4[i];
    }
    __syncthreads();

    const int wgid = __builtin_amdgcn_readfirstlane(blockIdx.x * 4 + wid);
    const int base = wgid * NPW;
    if (base >= N_ATOMS) return;

    float (*hb)[8] = hbuf[wid];
    const float s3 = 1.7320508075688772f, s15 = 3.872983346207417f;
    const float s5h = 1.118033988749895f, s15h = 1.9364916731037085f;

    auto clampn = [&](int i) { int nn = base + i; return nn < N_ATOMS ? nn : N_ATOMS - 1; };
    int s0v = edge_src[clampn(0) * DEG + lcol];
    int s1v = edge_src[clampn(1) * DEG + lcol];
    uint4 xu0 = *(const uint4*)(x_bf + s0v * 32 + quad * 8);
    float4 ev0 = evec[(size_t)clampn(0) * DEG + lcol];   // coalesced, quad-broadcast
    float e0v[NB];
    {
        const float* p = edge_attr + ((size_t)clampn(0) * DEG + lcol) * NB;
        #pragma unroll
        for (int b = 0; b < NB; b++) e0v[b] = p[b];
    }

    #pragma unroll 1
    for (int i = 0; i < NPW; i++) {
        const int n = base + i;
        if (n >= N_ATOMS) break;
        // ---- prefetch next stage ----
        int s2v = edge_src[clampn(i + 2 < NPW ? i + 2 : i) * DEG + lcol];
        uint4 xu1 = *(const uint4*)(x_bf + s1v * 32 + quad * 8);
        float4 ev1 = evec[(size_t)clampn(i + 1 < NPW ? i + 1 : i) * DEG + lcol];
        float e1v[NB];
        {
            const float* p = edge_attr + ((size_t)clampn(i + 1 < NPW ? i + 1 : i) * DEG + lcol) * NB;
            #pragma unroll
            for (int b = 0; b < NB; b++) e1v[b] = p[b];
        }
        // ---- unpack this node's x slice ----
        float xf[8];
        xf[0] = bf_lo(xu0.x); xf[1] = bf_hi(xu0.x);
        xf[2] = bf_lo(xu0.y); xf[3] = bf_hi(xu0.y);
        xf[4] = bf_lo(xu0.z); xf[5] = bf_hi(xu0.z);
        xf[6] = bf_lo(xu0.w); xf[7] = bf_hi(xu0.w);

        // ---- h-factors for node n (lanes 0..15): [sh1(3), sh2(5)] ----
        if (lane < 16) {
            const float vx = ev0.x, vy = ev0.y, vz = ev0.z;
            hb[lane][0] = s3 * vx;  hb[lane][1] = s3 * vy;  hb[lane][2] = s3 * vz;
            hb[lane][3] = s15 * vx * vy;
            hb[lane][4] = s15 * vy * vz;
            hb[lane][5] = s5h * (2.f * vz * vz - vx * vx - vy * vy);
            hb[lane][6] = s15 * vx * vz;
            hb[lane][7] = s15h * (vx * vx - vy * vy);
        }
        // ---- MFMA: 7 K-steps x 2 N-tiles (folded weights) ----
        floatx4 acc0 = {0.f,0.f,0.f,0.f}, acc1 = {0.f,0.f,0.f,0.f};
        #pragma unroll
        for (int s = 0; s < 7; s++) {
            const float eb = e0v[s];
            union { short8 v; unsigned u[4]; } af;
            #pragma unroll
            for (int j = 0; j < 8; j += 2) {
                float2 pr; pr.x = xf[j] * eb; pr.y = xf[j + 1] * eb;
                __hip_bfloat162 bb = __float22bfloat162_rn(pr);
                af.u[j >> 1] = *(unsigned*)&bb;
            }
            acc0 = __builtin_amdgcn_mfma_f32_16x16x32_bf16(af.v, wfrag[(s*NT+0)*64 + lane], acc0, 0, 0, 0);
            acc1 = __builtin_amdgcn_mfma_f32_16x16x32_bf16(af.v, wfrag[(s*NT+1)*64 + lane], acc1, 0, 0, 0);
        }
        // ---- epilogue: produce bf16 z-row (63 vals + pad) directly ----
        // acc cols: o=lcol (acc0), o=16+lcol (acc1); lane's D-edges e=quad*4+r.
        float4 hA[4], hB[4];
        #pragma unroll
        for (int r = 0; r < 4; r++) {
            int e = quad * 4 + r;
            hA[r] = *(const float4*)&hb[e][0];   // sh1 x,y,z | sh2 m0
            hB[r] = *(const float4*)&hb[e][4];   // sh2 m1..m4
        }
        unsigned short* sr = zbuf + (size_t)n * ZROW;
        const bool useA = (lcol >= 14);          // z2 source: acc0 cols 14,15 else acc1 cols 0..4
        float v0 = acc0[0] + acc0[1] + acc0[2] + acc0[3];
        float u0 = 0.f, u1 = 0.f, u2 = 0.f;
        float t0 = 0.f, t1 = 0.f, t2 = 0.f, t3 = 0.f, t4 = 0.f;
        #pragma unroll
        for (int r = 0; r < 4; r++) {
            float m0 = acc0[r], m1 = acc1[r];
            u0 += m0 * hA[r].x; u1 += m0 * hA[r].y; u2 += m0 * hA[r].z;
            float mz = useA ? m0 : m1;
            t0 += mz * hA[r].w; t1 += mz * hB[r].x; t2 += mz * hB[r].y;
            t3 += mz * hB[r].z; t4 += mz * hB[r].w;
        }
        v0 = wred4(v0);
        u0 = wred4(u0); u1 = wred4(u1); u2 = wred4(u2);
        t0 = wred4(t0); t1 = wred4(t1); t2 = wred4(t2); t3 = wred4(t3); t4 = wred4(t4);
        if (quad == 0) {
            if (lcol < 7) sr[lcol * 8] = bfbits(v0);                // c=0
            else if (lcol < 14) {                                   // c=1..3 (sh1)
                int b = lcol - 7;
                sr[b * 8 + 1] = bfbits(u0); sr[b * 8 + 2] = bfbits(u1); sr[b * 8 + 3] = bfbits(u2);
            }
            if (lcol >= 14 || lcol < 5) {                           // c=4..8 (sh2)
                int b = useA ? (lcol - 14) : (lcol + 2);
                sr[b * 8 + 4] = bfbits(t0); sr[b * 8 + 5] = bfbits(t1); sr[b * 8 + 6] = bfbits(t2);
                sr[b * 8 + 7] = bfbits(t3); sr[56 + b] = bfbits(t4);
            }
            if (lcol == 5) sr[63] = 0;   // pad (must be finite)
        }
        // ---- rotate pipeline ----
        s0v = s1v; s1v = s2v;
        xu0 = xu1; ev0 = ev1;
        #pragma unroll
        for (int b = 0; b < NB; b++) e0v[b] = e1v[b];
    }
}

// ---------------- K3 (R12-verified): 64 edges/wave; c8 via shfl --------------
__global__ __launch_bounds__(256, 4) void k3_g(const float4* __restrict__ evec,
        const float* __restrict__ edge_attr, const int* __restrict__ edge_src,
        const unsigned short* __restrict__ zbuf, float* __restrict__ out) {
    const int tid  = threadIdx.x;
    const int wid  = tid >> 6;
    const int lane = tid & 63;
    const int g    = lane >> 3;                 // edge-group (0..7)
    const int r    = lane & 7;                  // role = b index
    const int wgid = __builtin_amdgcn_readfirstlane(blockIdx.x * 4 + wid);
    const int ebase = wgid * 64;                // 64 edges = 4 dst nodes
    const int nbase = ebase >> 4;

    // ---- issue loads up front ----
    int sj[8];
    #pragma unroll
    for (int j = 0; j < 8; j++) sj[j] = edge_src[ebase + j * 8 + g];

    uint4 zq[8];                                // 8 lines/instr, 64 lines/wave
    #pragma unroll
    for (int j = 0; j < 8; j++)
        zq[j] = *(const uint4*)(zbuf + (size_t)sj[j] * ZROW + r * 8);

    float4 ev[8];                               // coalesced 128 B/instr
    #pragma unroll
    for (int j = 0; j < 8; j++) ev[j] = evec[ebase + j * 8 + g];

    float eav[8];                               // coalesced 224 B/instr
    #pragma unroll
    for (int j = 0; j < 8; j++)
        eav[j] = (r < NB) ? edge_attr[(size_t)(ebase + j * 8 + g) * NB + r] : 0.f;

    // ---- compute ----
    const float s3 = 1.7320508075688772f, s15 = 3.872983346207417f;
    const float s5h = 1.118033988749895f, s15h = 1.9364916731037085f;
    float accA = 0.f, accB = 0.f, accC = 0.f, accD = 0.f;   // nodes 0..3
    const int src7 = lane | 7;

    #pragma unroll
    for (int j = 0; j < 8; j++) {
        const float4 v = ev[j];
        const float h1 = s3 * v.x, h2 = s3 * v.y, h3 = s3 * v.z;
        const float h4 = s15 * v.x * v.y, h5 = s15 * v.y * v.z;
        const float h6 = s5h * (2.f * v.z * v.z - v.x * v.x - v.y * v.y);
        const float h7 = s15 * v.x * v.z, h8 = s15h * (v.x * v.x - v.y * v.y);

        const uint4 z = zq[j];
        // c8[b=r]: halfword r of lane|7's chunk (slots 56..63) — R5-verified
        const unsigned w0 = (unsigned)__shfl((int)z.x, src7, 64);
        const unsigned w1 = (unsigned)__shfl((int)z.y, src7, 64);
        const unsigned w2 = (unsigned)__shfl((int)z.z, src7, 64);
        const unsigned w3 = (unsigned)__shfl((int)z.w, src7, 64);
        const unsigned wa = (r & 4) ? w2 : w0;
        const unsigned wb = (r & 4) ? w3 : w1;
        const unsigned wc = (r & 2) ? wb : wa;
        const float c8 = (r & 1) ? bf_hi(wc) : bf_lo(wc);

        float t = bf_lo(z.x)
                + h1 * bf_hi(z.x) + h2 * bf_lo(z.y) + h3 * bf_hi(z.y)
                + h4 * bf_lo(z.z) + h5 * bf_hi(z.z) + h6 * bf_lo(z.w)
                + h7 * bf_hi(z.w) + h8 * c8;
        float p = eav[j] * t;                   // r==7 lane contributes 0
        if (j < 2)      accA += p;
        else if (j < 4) accB += p;
        else if (j < 6) accC += p;
        else            accD += p;
    }

    // 4 full-wave reductions (one per node), one atomic each
    #pragma unroll
    for (int p = 0; p < 4; p++) {
        float a = (p == 0) ? accA : (p == 1) ? accB : (p == 2) ? accC : accD;
        #pragma unroll
        for (int off = 32; off >= 1; off >>= 1) a += __shfl_xor(a, off, 64);
        if (lane == p)
            atomicAdd(out + (nbase + p) / 50, a * 0.035355339059327376f);  // 0.25/sqrt(50)
    }
}

extern "C" void kernel_launch(void* const* d_in, const int* in_sizes, int n_in,
                              void* d_out, int out_size, void* d_ws, size_t ws_size,
                              hipStream_t stream) {
    const float* pos  = (const float*)d_in[0];
    const float* x    = (const float*)d_in[1];
    const float* ea   = (const float*)d_in[2];
    const float* W1_0 = (const float*)d_in[3];
    const float* W1_1 = (const float*)d_in[4];
    const float* W1_2 = (const float*)d_in[5];
    const float* W2_0 = (const float*)d_in[6];
    const float* W2_1 = (const float*)d_in[7];
    const float* W2_2 = (const float*)d_in[8];
    const int*   esrc = (const int*)d_in[9];
    float* out = (float*)d_out;

    char* ws = (char*)d_ws;
    unsigned short* Vfrag = (unsigned short*)ws;                         // 14336 B
    unsigned short* zbuf  = (unsigned short*)(ws + 32768);               // 6.4 MB (bf16 rows)
    unsigned short* x_bf  = (unsigned short*)(ws + 32768 + 6400000);     // 3.2 MB
    float4*         evec  = (float4*)(ws + 32768 + 6400000 + 3200000);   // 12.8 MB

    hipLaunchKernelGGL(k_prep, dim3((N_ATOMS * 32 + 255) / 256), dim3(256), 0, stream,
                       W1_0, W1_1, W1_2, W2_0, W2_1, W2_2, x, pos, esrc,
                       Vfrag, x_bf, evec, out);
    hipLaunchKernelGGL(k2_s, dim3((N_ATOMS / NPW + 3) / 4), dim3(256), 0, stream,
                       evec, x_bf, ea, esrc, Vfrag, zbuf);
    hipLaunchKernelGGL(k3_g, dim3(N_EDGES / 64 / 4), dim3(256), 0, stream,
                       evec, ea, esrc, zbuf, out);
}